// Round 1
// baseline (6985.594 us; speedup 1.0000x reference)
//
#include <hip/hip_runtime.h>
#include <hip/hip_bf16.h>
#include <math.h>

#define N_NODES 20000
#define N_EDGES 100000
#define N_GRAPHS 200
#define NPG 100
#define EPG 500
#define TOPK 125
#define D_IN 64
#define EMB 300
#define H2 600
#define H4 1200
#define NLAYERS 5
#define NOUT 10

static inline int cdiv(int a, int b) { return (a + b - 1) / b; }

// ---------------- generic tiled fp32 GEMM: C[N,M] = A[N,K] @ B[K,M] + bias, opt relu
template<int RELU>
__global__ void gemm_bias(const float* __restrict__ A, const float* __restrict__ B,
                          const float* __restrict__ bias, float* __restrict__ C,
                          int N, int K, int M) {
    __shared__ float As[16][65];
    __shared__ float Bs[16][65];
    int tid = threadIdx.x;
    int tx = tid & 15, ty = tid >> 4;
    int m0 = blockIdx.y * 64;  // row block
    int n0 = blockIdx.x * 64;  // col block
    float c[4][4] = {};
    for (int k0 = 0; k0 < K; k0 += 16) {
#pragma unroll
        for (int l = 0; l < 4; ++l) {
            int idx = tid + l * 256;
            int k = idx & 15, m = idx >> 4;
            int gm = m0 + m, gk = k0 + k;
            As[k][m] = (gm < N && gk < K) ? A[(size_t)gm * K + gk] : 0.f;
        }
#pragma unroll
        for (int l = 0; l < 4; ++l) {
            int idx = tid + l * 256;
            int n = idx & 63, k = idx >> 6;
            int gk = k0 + k, gn = n0 + n;
            Bs[k][n] = (gk < K && gn < M) ? B[(size_t)gk * M + gn] : 0.f;
        }
        __syncthreads();
#pragma unroll
        for (int k = 0; k < 16; ++k) {
            float a[4], b[4];
#pragma unroll
            for (int i = 0; i < 4; ++i) a[i] = As[k][ty * 4 + i];
#pragma unroll
            for (int j = 0; j < 4; ++j) b[j] = Bs[k][tx * 4 + j];
#pragma unroll
            for (int i = 0; i < 4; ++i)
#pragma unroll
                for (int j = 0; j < 4; ++j) c[i][j] += a[i] * b[j];
        }
        __syncthreads();
    }
#pragma unroll
    for (int i = 0; i < 4; ++i) {
        int gm = m0 + ty * 4 + i;
        if (gm >= N) continue;
#pragma unroll
        for (int j = 0; j < 4; ++j) {
            int gn = n0 + tx * 4 + j;
            if (gn >= M) continue;
            float v = c[i][j] + (bias ? bias[gn] : 0.f);
            if (RELU) v = fmaxf(v, 0.f);
            C[(size_t)gm * M + gn] = v;
        }
    }
}

// ---------------- scatter aggregation: agg[dst] += h[src] * (ew?)
__global__ void scatter_agg(const float* __restrict__ h, const int* __restrict__ src,
                            const int* __restrict__ dst, const float* __restrict__ ew,
                            float* __restrict__ agg, int E) {
    long idx = (long)blockIdx.x * blockDim.x + threadIdx.x;
    if (idx >= (long)E * EMB) return;
    int e = (int)(idx / EMB);
    int c = (int)(idx - (long)e * EMB);
    float m = h[(size_t)src[e] * EMB + c];
    if (ew) m *= ew[e];
    atomicAdd(&agg[(size_t)dst[e] * EMB + c], m);
}

// ---------------- z = (1+eps[l])*h + agg  (in place into agg)
__global__ void zform(const float* __restrict__ h, float* __restrict__ zagg,
                      const float* __restrict__ eps, int l, int n) {
    int i = blockIdx.x * blockDim.x + threadIdx.x;
    if (i < n) zagg[i] = (1.f + eps[l]) * h[i] + zagg[i];
}

// ---------------- edge score: score[e] = relu(u[src]+v[dst]) . W2 + b2   (b1 folded into u)
__global__ void edge_score(const float* __restrict__ u, const float* __restrict__ v,
                           const float* __restrict__ W2, const float* __restrict__ b2,
                           const int* __restrict__ src, const int* __restrict__ dst,
                           float* __restrict__ score, int E, int node_base) {
    int e = blockIdx.x * 4 + (threadIdx.x >> 6);
    int lane = threadIdx.x & 63;
    if (e >= E) return;
    const float* up = u + (size_t)(src[e] - node_base) * H4;
    const float* vp = v + (size_t)(dst[e] - node_base) * H4;
    float acc = 0.f;
    for (int j = lane; j < H4; j += 64) {
        float hj = up[j] + vp[j];
        hj = fmaxf(hj, 0.f);
        acc += hj * W2[j];
    }
#pragma unroll
    for (int o = 32; o > 0; o >>= 1) acc += __shfl_down(acc, o, 64);
    if (lane == 0) score[e] = acc + b2[0];
}

// ---------------- per-graph top-125 of 500 contiguous edges via bitonic sort
__global__ void topk_kernel(const float* __restrict__ score, const int* __restrict__ src,
                            const int* __restrict__ dst, int* __restrict__ c_src,
                            int* __restrict__ c_dst, float* __restrict__ c_w,
                            float* __restrict__ mask) {
    __shared__ float s[512];
    __shared__ short sidx[512];
    int g = blockIdx.x, t = threadIdx.x;
    int base = g * EPG;
    s[t] = (t < EPG) ? score[base + t] : -1e30f;
    sidx[t] = (short)t;
    __syncthreads();
    for (int k = 2; k <= 512; k <<= 1) {
        for (int j = k >> 1; j > 0; j >>= 1) {
            int ixj = t ^ j;
            if (ixj > t) {
                float a = s[t], b = s[ixj];
                bool desc = ((t & k) == 0);
                bool sw = desc ? (a < b) : (a > b);
                if (sw) {
                    s[t] = b; s[ixj] = a;
                    short tmp = sidx[t]; sidx[t] = sidx[ixj]; sidx[ixj] = tmp;
                }
            }
            __syncthreads();
        }
    }
    if (t < TOPK) {
        int e = base + sidx[t];
        int sn = src[e], dn = dst[e];
        c_src[g * TOPK + t] = sn;
        c_dst[g * TOPK + t] = dn;
        c_w[g * TOPK + t] = 1.f / (1.f + expf(-s[t]));
        mask[sn] = 1.f;
        mask[dn] = 1.f;
    }
}

// ---------------- masked mean pool per graph + linear head
__global__ void pool_pred(const float* __restrict__ hc, const float* __restrict__ mask,
                          const float* __restrict__ W, const float* __restrict__ b,
                          float* __restrict__ out) {
    int g = blockIdx.x;
    int t = threadIdx.x;
    __shared__ float mloc[NPG];
    __shared__ float pooled[EMB];
    __shared__ float cnt;
    if (t < NPG) mloc[t] = mask[g * NPG + t];
    __syncthreads();
    if (t == 0) {
        float c = 0.f;
        for (int n = 0; n < NPG; ++n) c += mloc[n];
        cnt = fmaxf(c, 1.f);
    }
    __syncthreads();
    for (int c0 = t; c0 < EMB; c0 += 256) {
        float acc = 0.f;
        for (int n = 0; n < NPG; ++n)
            acc += mloc[n] * hc[((size_t)g * NPG + n) * EMB + c0];
        pooled[c0] = acc / cnt;
    }
    __syncthreads();
    if (t < NOUT) {
        float acc = b[t];
        for (int c0 = 0; c0 < EMB; ++c0) acc += pooled[c0] * W[c0 * NOUT + t];
        out[g * NOUT + t] = acc;
    }
}

extern "C" void kernel_launch(void* const* d_in, const int* in_sizes, int n_in,
                              void* d_out, int out_size, void* d_ws, size_t ws_size,
                              hipStream_t stream) {
    const float* x       = (const float*)d_in[0];
    const int*   eidx    = (const int*)d_in[1];
    // d_in[2] batch_vec, d_in[3] num_graphs: implied by static layout
    const float* enc_in_W = (const float*)d_in[4];
    const float* enc_in_b = (const float*)d_in[5];
    const float* enc_W1   = (const float*)d_in[6];
    const float* enc_b1   = (const float*)d_in[7];
    const float* enc_W2   = (const float*)d_in[8];
    const float* enc_b2   = (const float*)d_in[9];
    const float* enc_eps  = (const float*)d_in[10];
    const float* att_W1   = (const float*)d_in[11];
    const float* att_b1   = (const float*)d_in[12];
    const float* att_W2   = (const float*)d_in[13];
    const float* att_b2   = (const float*)d_in[14];
    const float* clf_in_W = (const float*)d_in[15];
    const float* clf_in_b = (const float*)d_in[16];
    const float* clf_W1   = (const float*)d_in[17];
    const float* clf_b1   = (const float*)d_in[18];
    const float* clf_W2   = (const float*)d_in[19];
    const float* clf_b2   = (const float*)d_in[20];
    const float* clf_eps  = (const float*)d_in[21];
    const float* pred_W   = (const float*)d_in[22];
    const float* pred_b   = (const float*)d_in[23];
    float* out = (float*)d_out;

    const int* src = eidx;
    const int* dst = eidx + N_EDGES;

    // workspace layout (floats)
    float* ws   = (float*)d_ws;
    float* h    = ws;                    // 6,000,000
    float* zagg = h + (size_t)N_NODES * EMB;      // 6,000,000
    float* tbuf = zagg + (size_t)N_NODES * EMB;   // 12,000,000 (wide MLP temp / u,v chunks)
    float* score = tbuf + (size_t)N_NODES * H2;   // 100,000
    float* c_w   = score + N_EDGES;               // 25,000
    float* mask  = c_w + N_GRAPHS * TOPK;         // 20,000
    int*   c_src = (int*)(mask + N_NODES);        // 25,000
    int*   c_dst = c_src + N_GRAPHS * TOPK;       // 25,000

    const size_t NH = (size_t)N_NODES * EMB;

    dim3 blk(256);
    dim3 g_in(cdiv(EMB, 64), cdiv(N_NODES, 64));       // N x 300
    dim3 g_w1(cdiv(H2, 64), cdiv(N_NODES, 64));        // N x 600
    dim3 g_w2(cdiv(EMB, 64), cdiv(N_NODES, 64));       // N x 300
    int scat_blocks_full = cdiv(N_EDGES * EMB, 256);
    int scat_blocks_cmp  = cdiv(N_GRAPHS * TOPK * EMB, 256);
    int zf_blocks = cdiv((int)NH, 256);

    // ---------- 1) encoder ----------
    gemm_bias<0><<<g_in, blk, 0, stream>>>(x, enc_in_W, enc_in_b, h, N_NODES, D_IN, EMB);
    for (int l = 0; l < NLAYERS; ++l) {
        hipMemsetAsync(zagg, 0, NH * sizeof(float), stream);
        scatter_agg<<<scat_blocks_full, blk, 0, stream>>>(h, src, dst, nullptr, zagg, N_EDGES);
        zform<<<zf_blocks, blk, 0, stream>>>(h, zagg, enc_eps, l, (int)NH);
        gemm_bias<1><<<g_w1, blk, 0, stream>>>(zagg, enc_W1 + (size_t)l * EMB * H2,
                                               enc_b1 + l * H2, tbuf, N_NODES, EMB, H2);
        if (l < NLAYERS - 1)
            gemm_bias<1><<<g_w2, blk, 0, stream>>>(tbuf, enc_W2 + (size_t)l * H2 * EMB,
                                                   enc_b2 + l * EMB, h, N_NODES, H2, EMB);
        else
            gemm_bias<0><<<g_w2, blk, 0, stream>>>(tbuf, enc_W2 + (size_t)l * H2 * EMB,
                                                   enc_b2 + l * EMB, h, N_NODES, H2, EMB);
    }

    // ---------- 2) edge scores (u/v factorization, 4 chunks of 50 graphs) ----------
    const int CH_NODES = N_NODES / 4;   // 5000
    const int CH_EDGES = N_EDGES / 4;   // 25000
    float* u = tbuf;                       // 5000 x 1200 = 6,000,000
    float* v = tbuf + (size_t)CH_NODES * H4;
    for (int cc = 0; cc < 4; ++cc) {
        int nb = cc * CH_NODES;
        int eb = cc * CH_EDGES;
        dim3 g_uv(cdiv(H4, 64), cdiv(CH_NODES, 64));
        gemm_bias<0><<<g_uv, blk, 0, stream>>>(h + (size_t)nb * EMB, att_W1, att_b1,
                                               u, CH_NODES, EMB, H4);
        gemm_bias<0><<<g_uv, blk, 0, stream>>>(h + (size_t)nb * EMB, att_W1 + (size_t)EMB * H4,
                                               nullptr, v, CH_NODES, EMB, H4);
        edge_score<<<cdiv(CH_EDGES, 4), blk, 0, stream>>>(u, v, att_W2, att_b2,
                                                          src + eb, dst + eb, score + eb,
                                                          CH_EDGES, nb);
    }

    // ---------- 3) top-K per graph + mask ----------
    hipMemsetAsync(mask, 0, N_NODES * sizeof(float), stream);
    topk_kernel<<<N_GRAPHS, 512, 0, stream>>>(score, src, dst, c_src, c_dst, c_w, mask);

    // ---------- 4) classifier on causal subgraph ----------
    gemm_bias<0><<<g_in, blk, 0, stream>>>(x, clf_in_W, clf_in_b, h, N_NODES, D_IN, EMB);
    for (int l = 0; l < NLAYERS; ++l) {
        hipMemsetAsync(zagg, 0, NH * sizeof(float), stream);
        scatter_agg<<<scat_blocks_cmp, blk, 0, stream>>>(h, c_src, c_dst, c_w, zagg,
                                                         N_GRAPHS * TOPK);
        zform<<<zf_blocks, blk, 0, stream>>>(h, zagg, clf_eps, l, (int)NH);
        gemm_bias<1><<<g_w1, blk, 0, stream>>>(zagg, clf_W1 + (size_t)l * EMB * H2,
                                               clf_b1 + l * H2, tbuf, N_NODES, EMB, H2);
        if (l < NLAYERS - 1)
            gemm_bias<1><<<g_w2, blk, 0, stream>>>(tbuf, clf_W2 + (size_t)l * H2 * EMB,
                                                   clf_b2 + l * EMB, h, N_NODES, H2, EMB);
        else
            gemm_bias<0><<<g_w2, blk, 0, stream>>>(tbuf, clf_W2 + (size_t)l * H2 * EMB,
                                                   clf_b2 + l * EMB, h, N_NODES, H2, EMB);
    }

    // ---------- 5) masked mean pool + prediction head ----------
    pool_pred<<<N_GRAPHS, 256, 0, stream>>>(h, mask, pred_W, pred_b, out);
}

// Round 2
// 4236.467 us; speedup vs baseline: 1.6489x; 1.6489x over previous
//
#include <hip/hip_runtime.h>
#include <hip/hip_bf16.h>
#include <math.h>

#define N_NODES 20000
#define N_EDGES 100000
#define N_GRAPHS 200
#define NPG 100
#define EPG 500
#define TOPK 125
#define D_IN 64
#define EMB 300
#define H2 600
#define H4 1200
#define NLAYERS 5
#define NOUT 10

// padded dims
#define NPAD 20096      // 157 * 128
#define EMBP 320        // pad of 300 (K and M)
#define H2P 640         // pad of 600
#define H4P 1216        // pad of 1200 (19*64)
#define TCH_ROWS 5120   // t-chunk rows (40 blocks of 128)

static inline int cdiv(int a, int b) { return (a + b - 1) / b; }

typedef __attribute__((ext_vector_type(8))) short bfrag;
typedef __attribute__((ext_vector_type(4))) float f32x4;

__device__ __forceinline__ ushort f2bf(float f) {
    unsigned u = __builtin_bit_cast(unsigned, f);
    unsigned r = u + 0x7FFFu + ((u >> 16) & 1u);
    return (ushort)(r >> 16);
}
__device__ __forceinline__ float bf2f(ushort h) {
    unsigned u = ((unsigned)h) << 16;
    return __builtin_bit_cast(float, u);
}

template<int NT>
__device__ __forceinline__ void split_planes(float v, ushort& p0, ushort& p1, ushort& p2) {
    p0 = f2bf(v);
    float r = v - bf2f(p0);
    p1 = f2bf(r);
    if (NT == 3) { r -= bf2f(p1); p2 = f2bf(r); } else { p2 = 0; }
}

// async 16B global->LDS copy; LDS dest is wave-uniform base (+ lane*16 by HW)
#define GLOAD_LDS16(gsrc, ldst)                                                   \
    __builtin_amdgcn_global_load_lds(                                             \
        (const __attribute__((address_space(1))) void*)(gsrc),                    \
        (__attribute__((address_space(3))) void*)(ldst), 16, 0, 0)

// ============================================================================
// MFMA GEMM: C[rows x M] = sum over plane products of A (rows x Kp, bf16 planes)
// times B^T stored as Bt[Mpad x Kp] bf16 planes.  BM=128, BN=64, 4 waves.
// EPI=0: write fp32 C (+bias, opt relu).  EPI=1: write NT bf16 planes.
// ============================================================================
template<int NT, int RELU, int EPI>
__launch_bounds__(256)
__global__ void mfma_gemm(const ushort* __restrict__ A0, const ushort* __restrict__ A1,
                          const ushort* __restrict__ A2,
                          const ushort* __restrict__ B0, const ushort* __restrict__ B1,
                          const ushort* __restrict__ B2,
                          const float* __restrict__ bias, int Kp, int Mvalid, int ldc,
                          float* __restrict__ Cf, ushort* __restrict__ C0,
                          ushort* __restrict__ C1, ushort* __restrict__ C2) {
    __shared__ char smem[NT * 8192 + NT * 4096];   // A planes (128x32x2B) + B planes (64x32x2B)
    const int tid = threadIdx.x;
    const int wave = tid >> 6, lane = tid & 63;
    const int wr = wave >> 1, wc = wave & 1;
    const long rowbase = (long)blockIdx.y * 128;
    const int n0 = blockIdx.x * 64;

    const ushort* Ap[3] = {A0, A1, A2};
    const ushort* Bp[3] = {B0, B1, B2};

    f32x4 acc[4][2] = {};

    // staging geometry (swizzled global source, linear LDS dest)
    const int arow0 = wave * 16 + (lane >> 2);         // A it=0 row; it=1 adds 64
    const int aq = lane & 3;
    const int brow = wave * 16 + (lane >> 2);          // B row (0..63)

    for (int k0 = 0; k0 < Kp; k0 += 32) {
        // ---- stage A planes (2 iters of 4KB) and B planes (1 iter of 4KB)
#pragma unroll
        for (int p = 0; p < NT; ++p) {
            {
                int r = arow0;
                int q = aq ^ ((r >> 1) & 3);
                const ushort* g = Ap[p] + (size_t)(rowbase + r) * Kp + k0 + q * 8;
                GLOAD_LDS16(g, smem + p * 8192 + wave * 1024);
            }
            {
                int r = arow0 + 64;
                int q = aq ^ ((r >> 1) & 3);
                const ushort* g = Ap[p] + (size_t)(rowbase + r) * Kp + k0 + q * 8;
                GLOAD_LDS16(g, smem + p * 8192 + 4096 + wave * 1024);
            }
            {
                int q = aq ^ ((brow >> 1) & 3);
                const ushort* g = Bp[p] + (size_t)(n0 + brow) * Kp + k0 + q * 8;
                GLOAD_LDS16(g, smem + NT * 8192 + p * 4096 + wave * 1024);
            }
        }
        __syncthreads();

        // ---- fragments + MFMA
        bfrag bfr[2][3];
#pragma unroll
        for (int n = 0; n < 2; ++n)
#pragma unroll
            for (int p = 0; p < NT; ++p) {
                int rB = wc * 32 + n * 16 + (lane & 15);
                int q = (lane >> 4) ^ ((rB >> 1) & 3);
                bfr[n][p] = *(const bfrag*)(smem + NT * 8192 + p * 4096 + rB * 64 + q * 16);
            }
#pragma unroll
        for (int m = 0; m < 4; ++m) {
            bfrag afr[3];
#pragma unroll
            for (int p = 0; p < NT; ++p) {
                int rA = wr * 64 + m * 16 + (lane & 15);
                int q = (lane >> 4) ^ ((rA >> 1) & 3);
                afr[p] = *(const bfrag*)(smem + p * 8192 + rA * 64 + q * 16);
            }
#pragma unroll
            for (int n = 0; n < 2; ++n) {
#pragma unroll
                for (int pa = 0; pa < NT; ++pa)
#pragma unroll
                    for (int pb = 0; pb < NT; ++pb)
                        if (pa + pb <= NT - 1)
                            acc[m][n] = __builtin_amdgcn_mfma_f32_16x16x32_bf16(
                                afr[pa], bfr[n][pb], acc[m][n], 0, 0, 0);
            }
        }
        __syncthreads();
    }

    // ---- epilogue.  C/D layout: col = lane&15, row = (lane>>4)*4 + e
    const int colc = lane & 15, rquad = lane >> 4;
#pragma unroll
    for (int m = 0; m < 4; ++m) {
#pragma unroll
        for (int n = 0; n < 2; ++n) {
            long grow0 = rowbase + wr * 64 + m * 16 + rquad * 4;
            int gcol = n0 + wc * 32 + n * 16 + colc;
            bool cvld = gcol < Mvalid;
            float bv = (bias != nullptr && cvld) ? bias[gcol] : 0.f;
#pragma unroll
            for (int e = 0; e < 4; ++e) {
                float v = acc[m][n][e] + bv;
                if (RELU) v = fmaxf(v, 0.f);
                if (!cvld) v = 0.f;
                size_t o = (size_t)(grow0 + e) * ldc + gcol;
                if (EPI == 0) {
                    Cf[o] = v;
                } else {
                    ushort p0, p1, p2;
                    split_planes<NT>(v, p0, p1, p2);
                    C0[o] = p0; C1[o] = p1;
                    if (NT == 3) C2[o] = p2;
                }
            }
        }
    }
}

// ============================================================================
// conversions
// ============================================================================
template<int NT>
__global__ void conv_w(const float* __restrict__ W, int K, int M, int Kp, int Mp,
                       ushort* __restrict__ P0, ushort* __restrict__ P1,
                       ushort* __restrict__ P2) {
    int idx = blockIdx.x * 256 + threadIdx.x;
    if (idx >= Mp * Kp) return;
    int m = idx / Kp, k = idx % Kp;
    float v = (m < M && k < K) ? W[(size_t)k * M + m] : 0.f;
    ushort p0, p1, p2;
    split_planes<NT>(v, p0, p1, p2);
    P0[idx] = p0; P1[idx] = p1;
    if (NT == 3) P2[idx] = p2;
}

template<int NT>
__global__ void conv_a(const float* __restrict__ X, int rows_valid, int ldx, int Kv, int Kp,
                       ushort* __restrict__ P0, ushort* __restrict__ P1,
                       ushort* __restrict__ P2, long total) {
    long idx = (long)blockIdx.x * 256 + threadIdx.x;
    if (idx >= total) return;
    int r = (int)(idx / Kp), k = (int)(idx % Kp);
    float v = (r < rows_valid && k < Kv) ? X[(size_t)r * ldx + k] : 0.f;
    ushort p0, p1, p2;
    split_planes<NT>(v, p0, p1, p2);
    P0[idx] = p0; P1[idx] = p1;
    if (NT == 3) P2[idx] = p2;
}

// ============================================================================
// adjacency build (transposed: At[g][src_local][dst_local] += w)
// ============================================================================
__global__ void build_At(const int* __restrict__ src, const int* __restrict__ dst,
                         const float* __restrict__ w, float* __restrict__ At, int E) {
    int e = blockIdx.x * 256 + threadIdx.x;
    if (e >= E) return;
    int s = src[e], d = dst[e];
    int g = s / NPG;
    atomicAdd(&At[(size_t)g * NPG * NPG + (size_t)(s - g * NPG) * NPG + (d - g * NPG)],
              w ? w[e] : 1.f);
}

// ============================================================================
// fused aggregation: z = At^T h + (1+eps) h, emitted as NT bf16 planes.
// one block per graph; A row reads are wave-uniform -> scalar cache.
// ============================================================================
template<int NT>
__global__ void agg_gemm(const float* __restrict__ h, const float* __restrict__ At,
                         const float* __restrict__ eps, int l,
                         ushort* __restrict__ z0, ushort* __restrict__ z1,
                         ushort* __restrict__ z2) {
    int g = blockIdx.x;
    int lane = threadIdx.x & 63;
    int rb = __builtin_amdgcn_readfirstlane((threadIdx.x >> 6) * 25);
    const float* Ag = At + (size_t)g * NPG * NPG;
    const float* hg = h + (size_t)g * NPG * EMBP;
    float ep = 1.f + eps[l];
#pragma unroll
    for (int strip = 0; strip < 5; ++strip) {
        int c = strip * 64 + lane;
        bool cv = c < EMB;
        float acc[25];
#pragma unroll
        for (int r = 0; r < 25; ++r) acc[r] = 0.f;
#pragma unroll 4
        for (int k = 0; k < NPG; ++k) {
            float hv = cv ? hg[k * EMBP + c] : 0.f;
            const float* ak = Ag + k * NPG + rb;
#pragma unroll
            for (int r = 0; r < 25; ++r) acc[r] += ak[r] * hv;
        }
#pragma unroll
        for (int r = 0; r < 25; ++r) {
            int row = g * NPG + rb + r;
            float z = cv ? acc[r] + ep * hg[(rb + r) * EMBP + c] : 0.f;
            ushort p0, p1, p2;
            split_planes<NT>(z, p0, p1, p2);
            size_t o = (size_t)row * EMBP + c;
            z0[o] = p0; z1[o] = p1;
            if (NT == 3) z2[o] = p2;
        }
    }
}

// ============================================================================
// edge score: relu(u[src]+v[dst]) . W2 + b2    (b1 folded into u)
// ============================================================================
__global__ void edge_score(const float* __restrict__ u, const float* __restrict__ v,
                           const float* __restrict__ W2, const float* __restrict__ b2,
                           const int* __restrict__ src, const int* __restrict__ dst,
                           float* __restrict__ score, int E, int node_base) {
    int e = blockIdx.x * 4 + (threadIdx.x >> 6);
    int lane = threadIdx.x & 63;
    if (e >= E) return;
    const float* up = u + (size_t)(src[e] - node_base) * H4P;
    const float* vp = v + (size_t)(dst[e] - node_base) * H4P;
    float acc = 0.f;
    for (int j = lane; j < H4; j += 64) {
        float hj = fmaxf(up[j] + vp[j], 0.f);
        acc += hj * W2[j];
    }
#pragma unroll
    for (int o = 32; o > 0; o >>= 1) acc += __shfl_down(acc, o, 64);
    if (lane == 0) score[e] = acc + b2[0];
}

// ============================================================================
// per-graph top-125 of 500 contiguous edges via bitonic sort
// ============================================================================
__global__ void topk_kernel(const float* __restrict__ score, const int* __restrict__ src,
                            const int* __restrict__ dst, int* __restrict__ c_src,
                            int* __restrict__ c_dst, float* __restrict__ c_w,
                            float* __restrict__ mask) {
    __shared__ float s[512];
    __shared__ short sidx[512];
    int g = blockIdx.x, t = threadIdx.x;
    int base = g * EPG;
    s[t] = (t < EPG) ? score[base + t] : -1e30f;
    sidx[t] = (short)t;
    __syncthreads();
    for (int k = 2; k <= 512; k <<= 1) {
        for (int j = k >> 1; j > 0; j >>= 1) {
            int ixj = t ^ j;
            if (ixj > t) {
                float a = s[t], b = s[ixj];
                bool desc = ((t & k) == 0);
                if (desc ? (a < b) : (a > b)) {
                    s[t] = b; s[ixj] = a;
                    short tmp = sidx[t]; sidx[t] = sidx[ixj]; sidx[ixj] = tmp;
                }
            }
            __syncthreads();
        }
    }
    if (t < TOPK) {
        int e = base + sidx[t];
        int sn = src[e], dn = dst[e];
        c_src[g * TOPK + t] = sn;
        c_dst[g * TOPK + t] = dn;
        c_w[g * TOPK + t] = 1.f / (1.f + expf(-s[t]));
        mask[sn] = 1.f;
        mask[dn] = 1.f;
    }
}

// ============================================================================
// masked mean pool + linear head (h stride EMBP)
// ============================================================================
__global__ void pool_pred(const float* __restrict__ hc, const float* __restrict__ mask,
                          const float* __restrict__ W, const float* __restrict__ b,
                          float* __restrict__ out) {
    int g = blockIdx.x, t = threadIdx.x;
    __shared__ float mloc[NPG];
    __shared__ float pooled[EMB];
    __shared__ float cnt;
    if (t < NPG) mloc[t] = mask[g * NPG + t];
    __syncthreads();
    if (t == 0) {
        float c = 0.f;
        for (int n = 0; n < NPG; ++n) c += mloc[n];
        cnt = fmaxf(c, 1.f);
    }
    __syncthreads();
    for (int c0 = t; c0 < EMB; c0 += 256) {
        float acc = 0.f;
        for (int n = 0; n < NPG; ++n)
            acc += mloc[n] * hc[((size_t)g * NPG + n) * EMBP + c0];
        pooled[c0] = acc / cnt;
    }
    __syncthreads();
    if (t < NOUT) {
        float acc = b[t];
        for (int c0 = 0; c0 < EMB; ++c0) acc += pooled[c0] * W[c0 * NOUT + t];
        out[g * NOUT + t] = acc;
    }
}

// ============================================================================
extern "C" void kernel_launch(void* const* d_in, const int* in_sizes, int n_in,
                              void* d_out, int out_size, void* d_ws, size_t ws_size,
                              hipStream_t stream) {
    const float* x        = (const float*)d_in[0];
    const int*   eidx     = (const int*)d_in[1];
    const float* enc_in_W = (const float*)d_in[4];
    const float* enc_in_b = (const float*)d_in[5];
    const float* enc_W1   = (const float*)d_in[6];
    const float* enc_b1   = (const float*)d_in[7];
    const float* enc_W2   = (const float*)d_in[8];
    const float* enc_b2   = (const float*)d_in[9];
    const float* enc_eps  = (const float*)d_in[10];
    const float* att_W1   = (const float*)d_in[11];
    const float* att_b1   = (const float*)d_in[12];
    const float* att_W2   = (const float*)d_in[13];
    const float* att_b2   = (const float*)d_in[14];
    const float* clf_in_W = (const float*)d_in[15];
    const float* clf_in_b = (const float*)d_in[16];
    const float* clf_W1   = (const float*)d_in[17];
    const float* clf_b1   = (const float*)d_in[18];
    const float* clf_W2   = (const float*)d_in[19];
    const float* clf_b2   = (const float*)d_in[20];
    const float* clf_eps  = (const float*)d_in[21];
    const float* pred_W   = (const float*)d_in[22];
    const float* pred_b   = (const float*)d_in[23];
    float* out = (float*)d_out;

    const int* src = eidx;
    const int* dst = eidx + N_EDGES;

    // ---------------- workspace layout (bytes) ----------------
    char* ws = (char*)d_ws;
    constexpr size_t SZ_H   = (size_t)NPAD * EMBP * 4;        // 25,722,880
    constexpr size_t SZ_ZP  = (size_t)NPAD * EMBP * 2;        // 12,861,440 per plane
    constexpr size_t SZ_TP  = (size_t)TCH_ROWS * H2P * 2;     //  6,553,600 per plane
    constexpr size_t SZ_WSP = (size_t)H2P * EMBP * 2;         //    409,600 per plane
    constexpr size_t SZ_ATP = (size_t)H4P * EMBP * 2;         //    778,240 per plane

    constexpr size_t OFF_H   = 0;
    constexpr size_t OFF_Z   = OFF_H + SZ_H;
    constexpr size_t OFF_T   = OFF_Z + 3 * SZ_ZP;
    constexpr size_t OFF_WSL = OFF_T + 3 * SZ_TP;
    constexpr size_t OFF_AT  = OFF_WSL + 6 * SZ_WSP;
    constexpr size_t OFF_SC  = OFF_AT + (size_t)N_GRAPHS * NPG * NPG * 4;
    constexpr size_t OFF_CW  = OFF_SC + (size_t)N_EDGES * 4;
    constexpr size_t OFF_MK  = OFF_CW + (size_t)N_GRAPHS * TOPK * 4;
    constexpr size_t OFF_CS  = OFF_MK + (size_t)N_NODES * 4;
    constexpr size_t OFF_CD  = OFF_CS + (size_t)N_GRAPHS * TOPK * 4;

    float*  h   = (float*)(ws + OFF_H);
    ushort* z0  = (ushort*)(ws + OFF_Z);
    ushort* z1  = (ushort*)(ws + OFF_Z + SZ_ZP);
    ushort* z2  = (ushort*)(ws + OFF_Z + 2 * SZ_ZP);
    ushort* t0  = (ushort*)(ws + OFF_T);
    ushort* t1  = (ushort*)(ws + OFF_T + SZ_TP);
    ushort* t2  = (ushort*)(ws + OFF_T + 2 * SZ_TP);
    ushort* w0p[3] = {(ushort*)(ws + OFF_WSL), (ushort*)(ws + OFF_WSL + SZ_WSP),
                      (ushort*)(ws + OFF_WSL + 2 * SZ_WSP)};
    ushort* w1p[3] = {(ushort*)(ws + OFF_WSL + 3 * SZ_WSP), (ushort*)(ws + OFF_WSL + 4 * SZ_WSP),
                      (ushort*)(ws + OFF_WSL + 5 * SZ_WSP)};
    float*  At    = (float*)(ws + OFF_AT);
    float*  score = (float*)(ws + OFF_SC);
    float*  c_w   = (float*)(ws + OFF_CW);
    float*  mask  = (float*)(ws + OFF_MK);
    int*    c_src = (int*)(ws + OFF_CS);
    int*    c_dst = (int*)(ws + OFF_CD);

    // overlays
    ushort* xp[3] = {z0, z1, z2};                                    // x planes in z region
    float*  u = (float*)(ws + OFF_T);                                // 12,451,840 B
    ushort* wup[3] = {(ushort*)(ws + OFF_T + 12451840),
                      (ushort*)(ws + OFF_T + 12451840 + SZ_ATP),
                      (ushort*)(ws + OFF_T + 12451840 + 2 * SZ_ATP)};
    ushort* wvp[3] = {(ushort*)(ws + OFF_T + 14786560),
                      (ushort*)(ws + OFF_T + 14786560 + SZ_ATP),
                      (ushort*)(ws + OFF_T + 14786560 + 2 * SZ_ATP)};
    float*  vbuf = (float*)(ws + OFF_Z);                             // 12,451,840 B
    ushort* hp[3] = {(ushort*)(ws + OFF_Z + 12451840),
                     (ushort*)(ws + OFF_Z + 12451840 + 1638400),
                     (ushort*)(ws + OFF_Z + 12451840 + 2 * 1638400)};

    const int chunk_start[4] = {0, 40, 80, 120};   // in 128-row blocks
    const int chunk_nb[4]    = {40, 40, 40, 37};

    // ================= Phase E: encoder (NT=3) =================
    conv_w<3><<<(EMBP * 64) / 256, 256, 0, stream>>>(enc_in_W, D_IN, EMB, 64, EMBP,
                                                     w0p[0], w0p[1], w0p[2]);
    conv_a<3><<<(int)(((long)NPAD * 64) / 256), 256, 0, stream>>>(
        x, N_NODES, D_IN, D_IN, 64, xp[0], xp[1], xp[2], (long)NPAD * 64);
    mfma_gemm<3, 0, 0><<<dim3(EMBP / 64, NPAD / 128), 256, 0, stream>>>(
        xp[0], xp[1], xp[2], w0p[0], w0p[1], w0p[2], enc_in_b, 64, EMB, EMBP,
        h, nullptr, nullptr, nullptr);

    hipMemsetAsync(At, 0, (size_t)N_GRAPHS * NPG * NPG * 4, stream);
    build_At<<<cdiv(N_EDGES, 256), 256, 0, stream>>>(src, dst, nullptr, At, N_EDGES);

    for (int l = 0; l < NLAYERS; ++l) {
        agg_gemm<3><<<N_GRAPHS, 256, 0, stream>>>(h, At, enc_eps, l, z0, z1, z2);
        conv_w<3><<<(H2P * EMBP) / 256, 256, 0, stream>>>(
            enc_W1 + (size_t)l * EMB * H2, EMB, H2, EMBP, H2P, w0p[0], w0p[1], w0p[2]);
        conv_w<3><<<(EMBP * H2P) / 256, 256, 0, stream>>>(
            enc_W2 + (size_t)l * H2 * EMB, H2, EMB, H2P, EMBP, w1p[0], w1p[1], w1p[2]);
        for (int c = 0; c < 4; ++c) {
            size_t r0 = (size_t)chunk_start[c] * 128;
            int nb = chunk_nb[c];
            mfma_gemm<3, 1, 1><<<dim3(H2P / 64, nb), 256, 0, stream>>>(
                z0 + r0 * EMBP, z1 + r0 * EMBP, z2 + r0 * EMBP,
                w0p[0], w0p[1], w0p[2], enc_b1 + l * H2, EMBP, H2, H2P,
                nullptr, t0, t1, t2);
            if (l < NLAYERS - 1)
                mfma_gemm<3, 1, 0><<<dim3(EMBP / 64, nb), 256, 0, stream>>>(
                    t0, t1, t2, w1p[0], w1p[1], w1p[2], enc_b2 + l * EMB, H2P, EMB, EMBP,
                    h + r0 * EMBP, nullptr, nullptr, nullptr);
            else
                mfma_gemm<3, 0, 0><<<dim3(EMBP / 64, nb), 256, 0, stream>>>(
                    t0, t1, t2, w1p[0], w1p[1], w1p[2], enc_b2 + l * EMB, H2P, EMB, EMBP,
                    h + r0 * EMBP, nullptr, nullptr, nullptr);
        }
    }

    // ================= Phase S: edge scores + topk =================
    conv_w<3><<<(H4P * EMBP) / 256, 256, 0, stream>>>(att_W1, EMB, H4, EMBP, H4P,
                                                      wup[0], wup[1], wup[2]);
    conv_w<3><<<(H4P * EMBP) / 256, 256, 0, stream>>>(att_W1 + (size_t)EMB * H4, EMB, H4,
                                                      EMBP, H4P, wvp[0], wvp[1], wvp[2]);
    for (int sc = 0; sc < 8; ++sc) {
        size_t nb0 = (size_t)sc * 2500;
        conv_a<3><<<(int)(((long)2560 * EMBP) / 256), 256, 0, stream>>>(
            h + nb0 * EMBP, 2560, EMBP, EMB, EMBP, hp[0], hp[1], hp[2], (long)2560 * EMBP);
        mfma_gemm<3, 0, 0><<<dim3(H4P / 64, 20), 256, 0, stream>>>(
            hp[0], hp[1], hp[2], wup[0], wup[1], wup[2], att_b1, EMBP, H4, H4P,
            u, nullptr, nullptr, nullptr);
        mfma_gemm<3, 0, 0><<<dim3(H4P / 64, 20), 256, 0, stream>>>(
            hp[0], hp[1], hp[2], wvp[0], wvp[1], wvp[2], nullptr, EMBP, H4, H4P,
            vbuf, nullptr, nullptr, nullptr);
        edge_score<<<cdiv(12500, 4), 256, 0, stream>>>(u, vbuf, att_W2, att_b2,
                                                       src + sc * 12500, dst + sc * 12500,
                                                       score + sc * 12500, 12500, (int)nb0);
    }
    hipMemsetAsync(mask, 0, N_NODES * 4, stream);
    topk_kernel<<<N_GRAPHS, 512, 0, stream>>>(score, src, dst, c_src, c_dst, c_w, mask);

    // ================= Phase C: classifier (NT=2) =================
    conv_w<2><<<(EMBP * 64) / 256, 256, 0, stream>>>(clf_in_W, D_IN, EMB, 64, EMBP,
                                                     w0p[0], w0p[1], w0p[2]);
    conv_a<2><<<(int)(((long)NPAD * 64) / 256), 256, 0, stream>>>(
        x, N_NODES, D_IN, D_IN, 64, xp[0], xp[1], xp[2], (long)NPAD * 64);
    mfma_gemm<2, 0, 0><<<dim3(EMBP / 64, NPAD / 128), 256, 0, stream>>>(
        xp[0], xp[1], nullptr, w0p[0], w0p[1], nullptr, clf_in_b, 64, EMB, EMBP,
        h, nullptr, nullptr, nullptr);

    hipMemsetAsync(At, 0, (size_t)N_GRAPHS * NPG * NPG * 4, stream);
    build_At<<<cdiv(N_GRAPHS * TOPK, 256), 256, 0, stream>>>(c_src, c_dst, c_w, At,
                                                             N_GRAPHS * TOPK);

    for (int l = 0; l < NLAYERS; ++l) {
        agg_gemm<2><<<N_GRAPHS, 256, 0, stream>>>(h, At, clf_eps, l, z0, z1, nullptr);
        conv_w<2><<<(H2P * EMBP) / 256, 256, 0, stream>>>(
            clf_W1 + (size_t)l * EMB * H2, EMB, H2, EMBP, H2P, w0p[0], w0p[1], w0p[2]);
        conv_w<2><<<(EMBP * H2P) / 256, 256, 0, stream>>>(
            clf_W2 + (size_t)l * H2 * EMB, H2, EMB, H2P, EMBP, w1p[0], w1p[1], w1p[2]);
        for (int c = 0; c < 4; ++c) {
            size_t r0 = (size_t)chunk_start[c] * 128;
            int nb = chunk_nb[c];
            mfma_gemm<2, 1, 1><<<dim3(H2P / 64, nb), 256, 0, stream>>>(
                z0 + r0 * EMBP, z1 + r0 * EMBP, nullptr,
                w0p[0], w0p[1], nullptr, clf_b1 + l * H2, EMBP, H2, H2P,
                nullptr, t0, t1, nullptr);
            if (l < NLAYERS - 1)
                mfma_gemm<2, 1, 0><<<dim3(EMBP / 64, nb), 256, 0, stream>>>(
                    t0, t1, nullptr, w1p[0], w1p[1], nullptr, clf_b2 + l * EMB, H2P, EMB, EMBP,
                    h + r0 * EMBP, nullptr, nullptr, nullptr);
            else
                mfma_gemm<2, 0, 0><<<dim3(EMBP / 64, nb), 256, 0, stream>>>(
                    t0, t1, nullptr, w1p[0], w1p[1], nullptr, clf_b2 + l * EMB, H2P, EMB, EMBP,
                    h + r0 * EMBP, nullptr, nullptr, nullptr);
        }
    }

    // ================= pool + head =================
    pool_pred<<<N_GRAPHS, 256, 0, stream>>>(h, mask, pred_W, pred_b, out);
}

// Round 3
// 3151.395 us; speedup vs baseline: 2.2167x; 1.3443x over previous
//
#include <hip/hip_runtime.h>
#include <hip/hip_bf16.h>
#include <math.h>

#define N_NODES 20000
#define N_EDGES 100000
#define N_GRAPHS 200
#define NPG 100
#define EPG 500
#define TOPK 125
#define D_IN 64
#define EMB 300
#define H2 600
#define H4 1200
#define NLAYERS 5
#define NOUT 10

// padded dims
#define NPAD 20096      // 157 * 128
#define EMBP 320        // pad of 300 (K and M)
#define H2P 640         // pad of 600
#define H4P 1216        // pad of 1200 (19*64)
#define TCH_ROWS 5120   // t-chunk rows (40 blocks of 128)

static inline int cdiv(int a, int b) { return (a + b - 1) / b; }

typedef __attribute__((ext_vector_type(8))) short bfrag;
typedef __attribute__((ext_vector_type(4))) float f32x4;

__device__ __forceinline__ ushort f2bf(float f) {
    unsigned u = __builtin_bit_cast(unsigned, f);
    unsigned r = u + 0x7FFFu + ((u >> 16) & 1u);
    return (ushort)(r >> 16);
}
__device__ __forceinline__ float bf2f(ushort h) {
    unsigned u = ((unsigned)h) << 16;
    return __builtin_bit_cast(float, u);
}

template<int NT>
__device__ __forceinline__ void split_planes(float v, ushort& p0, ushort& p1, ushort& p2) {
    p0 = f2bf(v);
    float r = v - bf2f(p0);
    p1 = f2bf(r);
    if (NT == 3) { r -= bf2f(p1); p2 = f2bf(r); } else { p2 = 0; }
}

// async 16B global->LDS copy; LDS dest is wave-uniform base (+ lane*16 by HW)
#define GLOAD_LDS16(gsrc, ldst)                                                   \
    __builtin_amdgcn_global_load_lds(                                             \
        (const __attribute__((address_space(1))) void*)(gsrc),                    \
        (__attribute__((address_space(3))) void*)(ldst), 16, 0, 0)

// ============================================================================
// MFMA GEMM: C[rows x M] = sum over plane products of A (rows x Kp, bf16 planes)
// times B^T stored as Bt[Mpad x Kp] bf16 planes.  BM=128, BN=64, 4 waves.
// EPI=0: write fp32 C (+bias, opt relu).  EPI=1: write NT bf16 planes.
// ============================================================================
template<int NT, int RELU, int EPI>
__launch_bounds__(256)
__global__ void mfma_gemm(const ushort* __restrict__ A0, const ushort* __restrict__ A1,
                          const ushort* __restrict__ A2,
                          const ushort* __restrict__ B0, const ushort* __restrict__ B1,
                          const ushort* __restrict__ B2,
                          const float* __restrict__ bias, int Kp, int Mvalid, int ldc,
                          float* __restrict__ Cf, ushort* __restrict__ C0,
                          ushort* __restrict__ C1, ushort* __restrict__ C2) {
    __shared__ char smem[NT * 8192 + NT * 4096];   // A planes (128x32x2B) + B planes (64x32x2B)
    const int tid = threadIdx.x;
    const int wave = tid >> 6, lane = tid & 63;
    const int wr = wave >> 1, wc = wave & 1;
    const long rowbase = (long)blockIdx.y * 128;
    const int n0 = blockIdx.x * 64;

    const ushort* Ap[3] = {A0, A1, A2};
    const ushort* Bp[3] = {B0, B1, B2};

    f32x4 acc[4][2] = {};

    // staging geometry (swizzled global source, linear LDS dest)
    const int arow0 = wave * 16 + (lane >> 2);         // A it=0 row; it=1 adds 64
    const int aq = lane & 3;
    const int brow = wave * 16 + (lane >> 2);          // B row (0..63)

    for (int k0 = 0; k0 < Kp; k0 += 32) {
        // ---- stage A planes (2 iters of 4KB) and B planes (1 iter of 4KB)
#pragma unroll
        for (int p = 0; p < NT; ++p) {
            {
                int r = arow0;
                int q = aq ^ ((r >> 1) & 3);
                const ushort* g = Ap[p] + (size_t)(rowbase + r) * Kp + k0 + q * 8;
                GLOAD_LDS16(g, smem + p * 8192 + wave * 1024);
            }
            {
                int r = arow0 + 64;
                int q = aq ^ ((r >> 1) & 3);
                const ushort* g = Ap[p] + (size_t)(rowbase + r) * Kp + k0 + q * 8;
                GLOAD_LDS16(g, smem + p * 8192 + 4096 + wave * 1024);
            }
            {
                int q = aq ^ ((brow >> 1) & 3);
                const ushort* g = Bp[p] + (size_t)(n0 + brow) * Kp + k0 + q * 8;
                GLOAD_LDS16(g, smem + NT * 8192 + p * 4096 + wave * 1024);
            }
        }
        __syncthreads();

        // ---- fragments + MFMA
        bfrag bfr[2][3];
#pragma unroll
        for (int n = 0; n < 2; ++n)
#pragma unroll
            for (int p = 0; p < NT; ++p) {
                int rB = wc * 32 + n * 16 + (lane & 15);
                int q = (lane >> 4) ^ ((rB >> 1) & 3);
                bfr[n][p] = *(const bfrag*)(smem + NT * 8192 + p * 4096 + rB * 64 + q * 16);
            }
#pragma unroll
        for (int m = 0; m < 4; ++m) {
            bfrag afr[3];
#pragma unroll
            for (int p = 0; p < NT; ++p) {
                int rA = wr * 64 + m * 16 + (lane & 15);
                int q = (lane >> 4) ^ ((rA >> 1) & 3);
                afr[p] = *(const bfrag*)(smem + p * 8192 + rA * 64 + q * 16);
            }
#pragma unroll
            for (int n = 0; n < 2; ++n) {
#pragma unroll
                for (int pa = 0; pa < NT; ++pa)
#pragma unroll
                    for (int pb = 0; pb < NT; ++pb)
                        if (pa + pb <= NT - 1)
                            acc[m][n] = __builtin_amdgcn_mfma_f32_16x16x32_bf16(
                                afr[pa], bfr[n][pb], acc[m][n], 0, 0, 0);
            }
        }
        __syncthreads();
    }

    // ---- epilogue.  C/D layout: col = lane&15, row = (lane>>4)*4 + e
    const int colc = lane & 15, rquad = lane >> 4;
#pragma unroll
    for (int m = 0; m < 4; ++m) {
#pragma unroll
        for (int n = 0; n < 2; ++n) {
            long grow0 = rowbase + wr * 64 + m * 16 + rquad * 4;
            int gcol = n0 + wc * 32 + n * 16 + colc;
            bool cvld = gcol < Mvalid;
            float bv = (bias != nullptr && cvld) ? bias[gcol] : 0.f;
#pragma unroll
            for (int e = 0; e < 4; ++e) {
                float v = acc[m][n][e] + bv;
                if (RELU) v = fmaxf(v, 0.f);
                if (!cvld) v = 0.f;
                size_t o = (size_t)(grow0 + e) * ldc + gcol;
                if (EPI == 0) {
                    Cf[o] = v;
                } else {
                    ushort p0, p1, p2;
                    split_planes<NT>(v, p0, p1, p2);
                    C0[o] = p0; C1[o] = p1;
                    if (NT == 3) C2[o] = p2;
                }
            }
        }
    }
}

// ============================================================================
// conversions
// ============================================================================
template<int NT>
__global__ void conv_w(const float* __restrict__ W, int K, int M, int Kp, int Mp,
                       ushort* __restrict__ P0, ushort* __restrict__ P1,
                       ushort* __restrict__ P2) {
    int idx = blockIdx.x * 256 + threadIdx.x;
    if (idx >= Mp * Kp) return;
    int m = idx / Kp, k = idx % Kp;
    float v = (m < M && k < K) ? W[(size_t)k * M + m] : 0.f;
    ushort p0, p1, p2;
    split_planes<NT>(v, p0, p1, p2);
    P0[idx] = p0; P1[idx] = p1;
    if (NT == 3) P2[idx] = p2;
}

template<int NT>
__global__ void conv_a(const float* __restrict__ X, int rows_valid, int ldx, int Kv, int Kp,
                       ushort* __restrict__ P0, ushort* __restrict__ P1,
                       ushort* __restrict__ P2, long total) {
    long idx = (long)blockIdx.x * 256 + threadIdx.x;
    if (idx >= total) return;
    int r = (int)(idx / Kp), k = (int)(idx % Kp);
    float v = (r < rows_valid && k < Kv) ? X[(size_t)r * ldx + k] : 0.f;
    ushort p0, p1, p2;
    split_planes<NT>(v, p0, p1, p2);
    P0[idx] = p0; P1[idx] = p1;
    if (NT == 3) P2[idx] = p2;
}

// ============================================================================
// adjacency build (transposed: At[g][src_local][dst_local] += w)
// ============================================================================
__global__ void build_At(const int* __restrict__ src, const int* __restrict__ dst,
                         const float* __restrict__ w, float* __restrict__ At, int E) {
    int e = blockIdx.x * 256 + threadIdx.x;
    if (e >= E) return;
    int s = src[e], d = dst[e];
    int g = s / NPG;
    atomicAdd(&At[(size_t)g * NPG * NPG + (size_t)(s - g * NPG) * NPG + (d - g * NPG)],
              w ? w[e] : 1.f);
}

// ============================================================================
// fused aggregation: z = At^T h + (1+eps) h, emitted as NT bf16 planes.
// grid = (graph, col-strip of 64); block = 4 waves x 25 rows each.
// A row reads are wave-uniform -> scalar cache; 1000 blocks feed HBM.
// ============================================================================
template<int NT>
__launch_bounds__(256)
__global__ void agg_gemm(const float* __restrict__ h, const float* __restrict__ At,
                         const float* __restrict__ eps, int l,
                         ushort* __restrict__ z0, ushort* __restrict__ z1,
                         ushort* __restrict__ z2) {
    int g = blockIdx.x;
    int strip = blockIdx.y;
    int lane = threadIdx.x & 63;
    int rb = __builtin_amdgcn_readfirstlane((threadIdx.x >> 6) * 25);
    const float* Ag = At + (size_t)g * NPG * NPG;
    const float* hg = h + (size_t)g * NPG * EMBP;
    float ep = 1.f + eps[l];

    int c = strip * 64 + lane;
    bool cv = c < EMB;
    float acc[25];
#pragma unroll
    for (int r = 0; r < 25; ++r) acc[r] = 0.f;
#pragma unroll 4
    for (int k = 0; k < NPG; ++k) {
        float hv = cv ? hg[k * EMBP + c] : 0.f;
        const float* ak = Ag + k * NPG + rb;
#pragma unroll
        for (int r = 0; r < 25; ++r) acc[r] += ak[r] * hv;
    }
#pragma unroll
    for (int r = 0; r < 25; ++r) {
        int row = g * NPG + rb + r;
        float z = cv ? acc[r] + ep * hg[(rb + r) * EMBP + c] : 0.f;
        ushort p0, p1, p2;
        split_planes<NT>(z, p0, p1, p2);
        size_t o = (size_t)row * EMBP + c;
        z0[o] = p0; z1[o] = p1;
        if (NT == 3) z2[o] = p2;
    }
}

// ============================================================================
// edge score: relu(u[src]+v[dst]) . W2 + b2    (b1 folded into u)
// ============================================================================
__global__ void edge_score(const float* __restrict__ u, const float* __restrict__ v,
                           const float* __restrict__ W2, const float* __restrict__ b2,
                           const int* __restrict__ src, const int* __restrict__ dst,
                           float* __restrict__ score, int E, int node_base) {
    int e = blockIdx.x * 4 + (threadIdx.x >> 6);
    int lane = threadIdx.x & 63;
    if (e >= E) return;
    const float* up = u + (size_t)(src[e] - node_base) * H4P;
    const float* vp = v + (size_t)(dst[e] - node_base) * H4P;
    float acc = 0.f;
    for (int j = lane; j < H4; j += 64) {
        float hj = fmaxf(up[j] + vp[j], 0.f);
        acc += hj * W2[j];
    }
#pragma unroll
    for (int o = 32; o > 0; o >>= 1) acc += __shfl_down(acc, o, 64);
    if (lane == 0) score[e] = acc + b2[0];
}

// ============================================================================
// per-graph top-125 of 500 contiguous edges via bitonic sort
// ============================================================================
__global__ void topk_kernel(const float* __restrict__ score, const int* __restrict__ src,
                            const int* __restrict__ dst, int* __restrict__ c_src,
                            int* __restrict__ c_dst, float* __restrict__ c_w,
                            float* __restrict__ mask) {
    __shared__ float s[512];
    __shared__ short sidx[512];
    int g = blockIdx.x, t = threadIdx.x;
    int base = g * EPG;
    s[t] = (t < EPG) ? score[base + t] : -1e30f;
    sidx[t] = (short)t;
    __syncthreads();
    for (int k = 2; k <= 512; k <<= 1) {
        for (int j = k >> 1; j > 0; j >>= 1) {
            int ixj = t ^ j;
            if (ixj > t) {
                float a = s[t], b = s[ixj];
                bool desc = ((t & k) == 0);
                if (desc ? (a < b) : (a > b)) {
                    s[t] = b; s[ixj] = a;
                    short tmp = sidx[t]; sidx[t] = sidx[ixj]; sidx[ixj] = tmp;
                }
            }
            __syncthreads();
        }
    }
    if (t < TOPK) {
        int e = base + sidx[t];
        int sn = src[e], dn = dst[e];
        c_src[g * TOPK + t] = sn;
        c_dst[g * TOPK + t] = dn;
        c_w[g * TOPK + t] = 1.f / (1.f + expf(-s[t]));
        mask[sn] = 1.f;
        mask[dn] = 1.f;
    }
}

// ============================================================================
// masked mean pool + linear head (h stride EMBP)
// ============================================================================
__global__ void pool_pred(const float* __restrict__ hc, const float* __restrict__ mask,
                          const float* __restrict__ W, const float* __restrict__ b,
                          float* __restrict__ out) {
    int g = blockIdx.x, t = threadIdx.x;
    __shared__ float mloc[NPG];
    __shared__ float pooled[EMB];
    __shared__ float cnt;
    if (t < NPG) mloc[t] = mask[g * NPG + t];
    __syncthreads();
    if (t == 0) {
        float c = 0.f;
        for (int n = 0; n < NPG; ++n) c += mloc[n];
        cnt = fmaxf(c, 1.f);
    }
    __syncthreads();
    for (int c0 = t; c0 < EMB; c0 += 256) {
        float acc = 0.f;
        for (int n = 0; n < NPG; ++n)
            acc += mloc[n] * hc[((size_t)g * NPG + n) * EMBP + c0];
        pooled[c0] = acc / cnt;
    }
    __syncthreads();
    if (t < NOUT) {
        float acc = b[t];
        for (int c0 = 0; c0 < EMB; ++c0) acc += pooled[c0] * W[c0 * NOUT + t];
        out[g * NOUT + t] = acc;
    }
}

// ============================================================================
extern "C" void kernel_launch(void* const* d_in, const int* in_sizes, int n_in,
                              void* d_out, int out_size, void* d_ws, size_t ws_size,
                              hipStream_t stream) {
    const float* x        = (const float*)d_in[0];
    const int*   eidx     = (const int*)d_in[1];
    const float* enc_in_W = (const float*)d_in[4];
    const float* enc_in_b = (const float*)d_in[5];
    const float* enc_W1   = (const float*)d_in[6];
    const float* enc_b1   = (const float*)d_in[7];
    const float* enc_W2   = (const float*)d_in[8];
    const float* enc_b2   = (const float*)d_in[9];
    const float* enc_eps  = (const float*)d_in[10];
    const float* att_W1   = (const float*)d_in[11];
    const float* att_b1   = (const float*)d_in[12];
    const float* att_W2   = (const float*)d_in[13];
    const float* att_b2   = (const float*)d_in[14];
    const float* clf_in_W = (const float*)d_in[15];
    const float* clf_in_b = (const float*)d_in[16];
    const float* clf_W1   = (const float*)d_in[17];
    const float* clf_b1   = (const float*)d_in[18];
    const float* clf_W2   = (const float*)d_in[19];
    const float* clf_b2   = (const float*)d_in[20];
    const float* clf_eps  = (const float*)d_in[21];
    const float* pred_W   = (const float*)d_in[22];
    const float* pred_b   = (const float*)d_in[23];
    float* out = (float*)d_out;

    const int* src = eidx;
    const int* dst = eidx + N_EDGES;

    // ---------------- workspace layout (bytes) ----------------
    char* ws = (char*)d_ws;
    constexpr size_t SZ_H   = (size_t)NPAD * EMBP * 4;        // 25,722,880
    constexpr size_t SZ_ZP  = (size_t)NPAD * EMBP * 2;        // 12,861,440 per plane
    constexpr size_t SZ_TP  = (size_t)TCH_ROWS * H2P * 2;     //  6,553,600 per plane
    constexpr size_t SZ_WSP = (size_t)H2P * EMBP * 2;         //    409,600 per plane
    constexpr size_t SZ_ATP = (size_t)H4P * EMBP * 2;         //    778,240 per plane

    constexpr size_t OFF_H   = 0;
    constexpr size_t OFF_Z   = OFF_H + SZ_H;
    constexpr size_t OFF_T   = OFF_Z + 3 * SZ_ZP;
    constexpr size_t OFF_WSL = OFF_T + 3 * SZ_TP;
    constexpr size_t OFF_AT  = OFF_WSL + 6 * SZ_WSP;
    constexpr size_t OFF_SC  = OFF_AT + (size_t)N_GRAPHS * NPG * NPG * 4;
    constexpr size_t OFF_CW  = OFF_SC + (size_t)N_EDGES * 4;
    constexpr size_t OFF_MK  = OFF_CW + (size_t)N_GRAPHS * TOPK * 4;
    constexpr size_t OFF_CS  = OFF_MK + (size_t)N_NODES * 4;
    constexpr size_t OFF_CD  = OFF_CS + (size_t)N_GRAPHS * TOPK * 4;

    float*  h   = (float*)(ws + OFF_H);
    ushort* z0  = (ushort*)(ws + OFF_Z);
    ushort* z1  = (ushort*)(ws + OFF_Z + SZ_ZP);
    ushort* z2  = (ushort*)(ws + OFF_Z + 2 * SZ_ZP);
    ushort* t0  = (ushort*)(ws + OFF_T);
    ushort* t1  = (ushort*)(ws + OFF_T + SZ_TP);
    ushort* t2  = (ushort*)(ws + OFF_T + 2 * SZ_TP);
    ushort* w0p[3] = {(ushort*)(ws + OFF_WSL), (ushort*)(ws + OFF_WSL + SZ_WSP),
                      (ushort*)(ws + OFF_WSL + 2 * SZ_WSP)};
    ushort* w1p[3] = {(ushort*)(ws + OFF_WSL + 3 * SZ_WSP), (ushort*)(ws + OFF_WSL + 4 * SZ_WSP),
                      (ushort*)(ws + OFF_WSL + 5 * SZ_WSP)};
    float*  At    = (float*)(ws + OFF_AT);
    float*  score = (float*)(ws + OFF_SC);
    float*  c_w   = (float*)(ws + OFF_CW);
    float*  mask  = (float*)(ws + OFF_MK);
    int*    c_src = (int*)(ws + OFF_CS);
    int*    c_dst = (int*)(ws + OFF_CD);

    // overlays
    ushort* xp[3] = {z0, z1, z2};                                    // x planes in z region
    float*  u = (float*)(ws + OFF_T);                                // 12,451,840 B
    ushort* wup[3] = {(ushort*)(ws + OFF_T + 12451840),
                      (ushort*)(ws + OFF_T + 12451840 + SZ_ATP),
                      (ushort*)(ws + OFF_T + 12451840 + 2 * SZ_ATP)};
    ushort* wvp[3] = {(ushort*)(ws + OFF_T + 14786560),
                      (ushort*)(ws + OFF_T + 14786560 + SZ_ATP),
                      (ushort*)(ws + OFF_T + 14786560 + 2 * SZ_ATP)};
    float*  vbuf = (float*)(ws + OFF_Z);                             // 12,451,840 B
    ushort* hp[3] = {(ushort*)(ws + OFF_Z + 12451840),
                     (ushort*)(ws + OFF_Z + 12451840 + 1638400),
                     (ushort*)(ws + OFF_Z + 12451840 + 2 * 1638400)};

    const int chunk_start[4] = {0, 40, 80, 120};   // in 128-row blocks
    const int chunk_nb[4]    = {40, 40, 40, 37};

    // ================= Phase E: encoder (NT=3) =================
    conv_w<3><<<(EMBP * 64) / 256, 256, 0, stream>>>(enc_in_W, D_IN, EMB, 64, EMBP,
                                                     w0p[0], w0p[1], w0p[2]);
    conv_a<3><<<(int)(((long)NPAD * 64) / 256), 256, 0, stream>>>(
        x, N_NODES, D_IN, D_IN, 64, xp[0], xp[1], xp[2], (long)NPAD * 64);
    mfma_gemm<3, 0, 0><<<dim3(EMBP / 64, NPAD / 128), 256, 0, stream>>>(
        xp[0], xp[1], xp[2], w0p[0], w0p[1], w0p[2], enc_in_b, 64, EMB, EMBP,
        h, nullptr, nullptr, nullptr);

    hipMemsetAsync(At, 0, (size_t)N_GRAPHS * NPG * NPG * 4, stream);
    build_At<<<cdiv(N_EDGES, 256), 256, 0, stream>>>(src, dst, nullptr, At, N_EDGES);

    for (int l = 0; l < NLAYERS; ++l) {
        agg_gemm<3><<<dim3(N_GRAPHS, 5), 256, 0, stream>>>(h, At, enc_eps, l, z0, z1, z2);
        conv_w<3><<<(H2P * EMBP) / 256, 256, 0, stream>>>(
            enc_W1 + (size_t)l * EMB * H2, EMB, H2, EMBP, H2P, w0p[0], w0p[1], w0p[2]);
        conv_w<3><<<(EMBP * H2P) / 256, 256, 0, stream>>>(
            enc_W2 + (size_t)l * H2 * EMB, H2, EMB, H2P, EMBP, w1p[0], w1p[1], w1p[2]);
        for (int c = 0; c < 4; ++c) {
            size_t r0 = (size_t)chunk_start[c] * 128;
            int nb = chunk_nb[c];
            mfma_gemm<3, 1, 1><<<dim3(H2P / 64, nb), 256, 0, stream>>>(
                z0 + r0 * EMBP, z1 + r0 * EMBP, z2 + r0 * EMBP,
                w0p[0], w0p[1], w0p[2], enc_b1 + l * H2, EMBP, H2, H2P,
                nullptr, t0, t1, t2);
            if (l < NLAYERS - 1)
                mfma_gemm<3, 1, 0><<<dim3(EMBP / 64, nb), 256, 0, stream>>>(
                    t0, t1, t2, w1p[0], w1p[1], w1p[2], enc_b2 + l * EMB, H2P, EMB, EMBP,
                    h + r0 * EMBP, nullptr, nullptr, nullptr);
            else
                mfma_gemm<3, 0, 0><<<dim3(EMBP / 64, nb), 256, 0, stream>>>(
                    t0, t1, t2, w1p[0], w1p[1], w1p[2], enc_b2 + l * EMB, H2P, EMB, EMBP,
                    h + r0 * EMBP, nullptr, nullptr, nullptr);
        }
    }

    // ================= Phase S: edge scores + topk =================
    conv_w<3><<<(H4P * EMBP) / 256, 256, 0, stream>>>(att_W1, EMB, H4, EMBP, H4P,
                                                      wup[0], wup[1], wup[2]);
    conv_w<3><<<(H4P * EMBP) / 256, 256, 0, stream>>>(att_W1 + (size_t)EMB * H4, EMB, H4,
                                                      EMBP, H4P, wvp[0], wvp[1], wvp[2]);
    for (int sc = 0; sc < 8; ++sc) {
        size_t nb0 = (size_t)sc * 2500;
        conv_a<3><<<(int)(((long)2560 * EMBP) / 256), 256, 0, stream>>>(
            h + nb0 * EMBP, 2560, EMBP, EMB, EMBP, hp[0], hp[1], hp[2], (long)2560 * EMBP);
        mfma_gemm<3, 0, 0><<<dim3(H4P / 64, 20), 256, 0, stream>>>(
            hp[0], hp[1], hp[2], wup[0], wup[1], wup[2], att_b1, EMBP, H4, H4P,
            u, nullptr, nullptr, nullptr);
        mfma_gemm<3, 0, 0><<<dim3(H4P / 64, 20), 256, 0, stream>>>(
            hp[0], hp[1], hp[2], wvp[0], wvp[1], wvp[2], nullptr, EMBP, H4, H4P,
            vbuf, nullptr, nullptr, nullptr);
        edge_score<<<cdiv(12500, 4), 256, 0, stream>>>(u, vbuf, att_W2, att_b2,
                                                       src + sc * 12500, dst + sc * 12500,
                                                       score + sc * 12500, 12500, (int)nb0);
    }
    hipMemsetAsync(mask, 0, N_NODES * 4, stream);
    topk_kernel<<<N_GRAPHS, 512, 0, stream>>>(score, src, dst, c_src, c_dst, c_w, mask);

    // ================= Phase C: classifier (NT=2) =================
    conv_w<2><<<(EMBP * 64) / 256, 256, 0, stream>>>(clf_in_W, D_IN, EMB, 64, EMBP,
                                                     w0p[0], w0p[1], w0p[2]);
    conv_a<2><<<(int)(((long)NPAD * 64) / 256), 256, 0, stream>>>(
        x, N_NODES, D_IN, D_IN, 64, xp[0], xp[1], xp[2], (long)NPAD * 64);
    mfma_gemm<2, 0, 0><<<dim3(EMBP / 64, NPAD / 128), 256, 0, stream>>>(
        xp[0], xp[1], nullptr, w0p[0], w0p[1], nullptr, clf_in_b, 64, EMB, EMBP,
        h, nullptr, nullptr, nullptr);

    hipMemsetAsync(At, 0, (size_t)N_GRAPHS * NPG * NPG * 4, stream);
    build_At<<<cdiv(N_GRAPHS * TOPK, 256), 256, 0, stream>>>(c_src, c_dst, c_w, At,
                                                             N_GRAPHS * TOPK);

    for (int l = 0; l < NLAYERS; ++l) {
        agg_gemm<2><<<dim3(N_GRAPHS, 5), 256, 0, stream>>>(h, At, clf_eps, l, z0, z1, nullptr);
        conv_w<2><<<(H2P * EMBP) / 256, 256, 0, stream>>>(
            clf_W1 + (size_t)l * EMB * H2, EMB, H2, EMBP, H2P, w0p[0], w0p[1], w0p[2]);
        conv_w<2><<<(EMBP * H2P) / 256, 256, 0, stream>>>(
            clf_W2 + (size_t)l * H2 * EMB, H2, EMB, H2P, EMBP, w1p[0], w1p[1], w1p[2]);
        for (int c = 0; c < 4; ++c) {
            size_t r0 = (size_t)chunk_start[c] * 128;
            int nb = chunk_nb[c];
            mfma_gemm<2, 1, 1><<<dim3(H2P / 64, nb), 256, 0, stream>>>(
                z0 + r0 * EMBP, z1 + r0 * EMBP, nullptr,
                w0p[0], w0p[1], nullptr, clf_b1 + l * H2, EMBP, H2, H2P,
                nullptr, t0, t1, nullptr);
            if (l < NLAYERS - 1)
                mfma_gemm<2, 1, 0><<<dim3(EMBP / 64, nb), 256, 0, stream>>>(
                    t0, t1, nullptr, w1p[0], w1p[1], nullptr, clf_b2 + l * EMB, H2P, EMB, EMBP,
                    h + r0 * EMBP, nullptr, nullptr, nullptr);
            else
                mfma_gemm<2, 0, 0><<<dim3(EMBP / 64, nb), 256, 0, stream>>>(
                    t0, t1, nullptr, w1p[0], w1p[1], nullptr, clf_b2 + l * EMB, H2P, EMB, EMBP,
                    h + r0 * EMBP, nullptr, nullptr, nullptr);
        }
    }

    // ================= pool + head =================
    pool_pred<<<N_GRAPHS, 256, 0, stream>>>(h, mask, pred_W, pred_b, out);
}